// Round 7
// baseline (66.928 us; speedup 1.0000x reference)
//
#include <hip/hip_runtime.h>
#include <hip/hip_bf16.h>
#include <stdint.h>

// KAN layer: out[n,o] = sum_j w[o,j] * spline(x[n,j]; coeffs[o,j,:]) + bias[o]
// N=1024, D_IN=128, D_OUT=128, K=8, Catmull-Rom, uniform grid [-1,1].
// fp32 in/out (proven R1/R2/R4).
//
// R6 post-mortem: dur flat vs R5 (65.1 vs 65.3) despite leaner structure.
// Kernel residual ~12.7us in both (R4 calibration: dur = 40us ws-fill +
// kernel + 12.4us fixed). Common factor: 1 wave/SIMD chip-wide -> zero TLP,
// all global/LDS latency exposed. R7 doubles waves/SIMD and removes the
// zero-pass:
//  - 512-thread blocks: 8 waves = 2 o-tiles(16) x 4-way K-split(256 k each)
//  - basis rows built in registers (R5-verified dynamic-index accumulate),
//    ONE ds_write_b128 per (row,j) task; no phase-0 zeroing, 2 barriers total
//  - W' fragments built in registers from global (lane (o,q) reads
//    w[o,j]*c[o,j,0:8] = 32B contiguous), no sB staging
// Grid 64x4 = 256 blocks = 1 block/CU, 2 waves/SIMD.
//
// MFMA 16x16x32 bf16 layouts (R5-verified, m89): A-frag lane holds
// A[m=lane&15][k=(lane>>4)*8+j]; B-frag same with o rows; C/D: col=lane&15,
// row=(lane>>4)*4+reg.

#define DIN 128
#define DOUT 128
#define KTOT 1024
#define MT 16
#define PADW 1032   // halfwords per basis row (1024+8) -> frag reads at BW floor

typedef unsigned int u32;
typedef unsigned short u16;
typedef __attribute__((ext_vector_type(8))) short bf16x8;
typedef __attribute__((ext_vector_type(4))) float f32x4;

union H8 { u16 s[8]; uint4 v; };

__device__ __forceinline__ u16 f2b(float f) {
    union { __hip_bfloat16 h; u16 u; } c;
    c.h = __float2bfloat16(f);   // RNE
    return c.u;
}

__global__ __launch_bounds__(512) void kan_mfma(
    const float* __restrict__ x, const float* __restrict__ coeffs,
    const float* __restrict__ weights, const float* __restrict__ bias,
    float* __restrict__ out)
{
    __shared__ __align__(16) u16 sA[MT * PADW];   // 33 KB basis (bf16)
    __shared__ float sC[8 * 256];                 // 8 KB wave partials

    const int tid  = threadIdx.x;
    const int wave = tid >> 6;
    const int lane = tid & 63;
    const int n0 = blockIdx.x * MT;               // 64 m-tiles
    const int og = blockIdx.y * 32;               // 4 o-groups of 32

    // ---- Phase 1: build basis rows in registers, one b128 store each ----
    #pragma unroll
    for (int it = 0; it < 4; ++it) {
        const int task = tid + it * 512;          // [0,2048) = 16 rows x 128 j
        const int row = task >> 7;
        const int j = task & 127;
        float xv = x[(n0 + row) * DIN + j];       // coalesced
        xv = fminf(fmaxf(xv, -1.0f), 1.0f);
        const float t = (xv + 1.0f) * 3.5f;       // h = 2/7
        int idx = (int)t; idx = idx > 6 ? 6 : idx;
        const float u = t - (float)idx;
        const float u2 = u * u, u3 = u2 * u;
        const float b0 = 0.5f * (-u3 + 2.0f * u2 - u);
        const float b1 = 0.5f * (3.0f * u3 - 5.0f * u2 + 2.0f);
        const float b2 = 0.5f * (-3.0f * u3 + 4.0f * u2 + u);
        const float b3 = 0.5f * (u3 - u2);
        float r[8];
        #pragma unroll
        for (int k = 0; k < 8; ++k) r[k] = 0.0f;
        const int i0 = idx > 0 ? idx - 1 : 0;     // accumulate handles clip
        const int i3 = idx < 6 ? idx + 2 : 7;
        r[i0] += b0; r[idx] += b1; r[idx + 1] += b2; r[i3] += b3;
        H8 h;
        #pragma unroll
        for (int k = 0; k < 8; ++k) h.s[k] = f2b(r[k]);
        *(uint4*)(sA + row * PADW + j * 8) = h.v;
    }
    __syncthreads();

    // ---- Phase 2: MFMA. wave -> (o-tile, K-quarter) ----
    const int ot = wave & 1;                      // o-tile within group
    const int kq = wave >> 1;                     // K quarter (256 k)
    const int mo = lane & 15;                     // A-row / B-o-row / D-col
    const int q  = lane >> 4;                     // k-quad

    const int orow = og + ot * 16 + mo;
    const float* cp = coeffs + orow * KTOT + kq * 256 + q * 8;
    const float* wp = weights + orow * DIN + kq * 32 + q;
    const u16*   ap = sA + mo * PADW + kq * 256 + q * 8;

    f32x4 acc = {0.0f, 0.0f, 0.0f, 0.0f};
    #pragma unroll
    for (int s = 0; s < 8; ++s) {
        bf16x8 af = *(const bf16x8*)(ap + s * 32);
        const float4 c0 = *(const float4*)(cp + s * 32);
        const float4 c1 = *(const float4*)(cp + s * 32 + 4);
        const float wv = wp[s * 4];
        bf16x8 bfr;
        bfr[0] = (short)f2b(c0.x * wv); bfr[1] = (short)f2b(c0.y * wv);
        bfr[2] = (short)f2b(c0.z * wv); bfr[3] = (short)f2b(c0.w * wv);
        bfr[4] = (short)f2b(c1.x * wv); bfr[5] = (short)f2b(c1.y * wv);
        bfr[6] = (short)f2b(c1.z * wv); bfr[7] = (short)f2b(c1.w * wv);
        acc = __builtin_amdgcn_mfma_f32_16x16x32_bf16(af, bfr, acc, 0, 0, 0);
    }

    // ---- Phase 3: reduce 4 K-partials per o-tile, + bias, store ----
    #pragma unroll
    for (int r = 0; r < 4; ++r)
        sC[wave * 256 + (q * 4 + r) * 16 + mo] = acc[r];
    __syncthreads();

    {
        const int tile = tid >> 8;                // o-tile (0/1)
        const int idx = tid & 255;
        const int row = idx >> 4, col = idx & 15;
        float v = sC[(0 + tile) * 256 + idx] + sC[(2 + tile) * 256 + idx]
                + sC[(4 + tile) * 256 + idx] + sC[(6 + tile) * 256 + idx];
        const int oc = og + tile * 16 + col;
        out[(n0 + row) * DOUT + oc] = v + bias[oc];
    }
}

extern "C" void kernel_launch(void* const* d_in, const int* in_sizes, int n_in,
                              void* d_out, int out_size, void* d_ws, size_t ws_size,
                              hipStream_t stream) {
    const float* x       = (const float*)d_in[0];
    const float* coeffs  = (const float*)d_in[1];
    const float* weights = (const float*)d_in[2];
    const float* bias    = (const float*)d_in[3];
    float* out = (float*)d_out;
    const int N = in_sizes[0] / DIN;              // 1024
    dim3 grid(N / MT, DOUT / 32);                 // 64 x 4 = 256 blocks
    kan_mfma<<<grid, 512, 0, stream>>>(x, coeffs, weights, bias, out);
}